// Round 2
// baseline (2331.706 us; speedup 1.0000x reference)
//
#include <hip/hip_runtime.h>

// Shapes: BS=256, C=256, H=W=16, HW=256, conv1: 1024->1024 3x3, conv2: 1024->512 3x3,
// cls: 512->512 1x1 (only diagonal of PSROI needed -> 2 dots/pixel).
//
// Workspace layout (bytes):
//   featT  @ 0          : bf16 [256 b][256 p][1024 ch]  = 134217728   (ch: r1|corr1|r2|corr2)
//   out1T  @ 134217728  : bf16 [256 b][256 p][1024 o]   = 134217728
//   W1b    @ 268435456  : bf16 [9][1024][1024]          = 18874368
//   W2b    @ 287309824  : bf16 [9][512][1024]           = 9437184
//   s1     @ 296747008  : f32  [256*256]                = 262144
//   s2     @ 297009152  : f32  [256*256]                = 262144
//   out2T  @ 0 (overlays featT, dead after conv1): bf16 [256][256][512] = 67108864
//
// SWIZZLED STORAGE FORMAT: every bf16 row-major tensor above stores each 64B slice
// (4 x 16B chunks) with chunk index XORed by ((row>>1)&3), where row = pixel p
// (featT/out1T/out2T) or output channel o (W1b/W2b). Rationale: LDS tiles are
// [row][32 u16]; ds_read_b128 fragment reads over 16 consecutive rows are 8-way
// bank-conflicted unswizzled (round 0: 1.72e8 conflict cycles). Pre-swizzling the
// global SOURCE of global_load_lds (round 1) fixed the conflicts but broke DMA
// coalescing (FETCH_SIZE 2.2x, kernel 34% slower). Baking the permutation into the
// stored data keeps gl2lds sources monotonic (round-0 traffic) while LDS reads use
// the XORed chunk offset (round-1 conflict-free pattern).

typedef __attribute__((ext_vector_type(8))) __bf16 bf16x8;
typedef __attribute__((ext_vector_type(4))) float f32x4;
typedef unsigned short u16;

template <bool B> struct BC { static constexpr bool value = B; };

__device__ __forceinline__ u16 f2bf(float f) {
  union { float f; unsigned u; } v; v.f = f;
  unsigned u = v.u;
  u += 0x7fffu + ((u >> 16) & 1u);   // RNE
  return (u16)(u >> 16);
}
__device__ __forceinline__ float bf2f(u16 h) {
  union { unsigned u; float f; } v; v.u = ((unsigned)h) << 16;
  return v.f;
}
__device__ __forceinline__ void gl2lds16(const void* g, void* l) {
  __builtin_amdgcn_global_load_lds(
      (__attribute__((address_space(1))) void*)(void*)g,
      (__attribute__((address_space(3))) void*)l, 16, 0, 0);
}

// ---------------------------------------------------------------------------
// Kernel 1: relu + channel-L2-norm scales + bf16 transpose to featT[b][p][ch].
// Stores in swizzled format: ch' = ch ^ (((p>>1)&3)<<3).
__global__ __launch_bounds__(256) void k_norm(const float* __restrict__ f1,
                                              const float* __restrict__ f2,
                                              u16* __restrict__ featT,
                                              float* __restrict__ s1,
                                              float* __restrict__ s2) {
  int bx = blockIdx.x;
  int b = bx >> 2;
  int p0 = (bx & 3) << 6;
  int t = threadIdx.x;
  int p = p0 + (t & 63);
  int cg = t >> 6;
  int sp3 = ((p >> 1) & 3) << 3;
  const float* F1 = f1 + ((size_t)b << 16);
  const float* F2 = f2 + ((size_t)b << 16);
  u16* FT = featT + (((size_t)(b << 8) + p) << 10);
  float ss1 = 0.f, ss2 = 0.f;
  for (int i = 0; i < 64; ++i) {
    int c = (cg << 6) + i;
    float v1 = F1[(c << 8) + p]; v1 = v1 > 0.f ? v1 : 0.f;
    float v2 = F2[(c << 8) + p]; v2 = v2 > 0.f ? v2 : 0.f;
    ss1 += v1 * v1; ss2 += v2 * v2;
    FT[c ^ sp3] = f2bf(v1);
    FT[512 + (c ^ sp3)] = f2bf(v2);
  }
  __shared__ float l1[256], l2[256];
  l1[t] = ss1; l2[t] = ss2;
  __syncthreads();
  if (t < 64) {
    float a = l1[t] + l1[t + 64] + l1[t + 128] + l1[t + 192];
    float c2 = l2[t] + l2[t + 64] + l2[t + 128] + l2[t + 192];
    int pp = (b << 8) + p0 + t;
    s1[pp] = 1.f / fmaxf(sqrtf(a), 1e-12f);
    s2[pp] = 1.f / fmaxf(sqrtf(c2), 1e-12f);
  }
}

// ---------------------------------------------------------------------------
// Kernel 2: weight repack fp32 [O][C][3][3] -> bf16 [tap][O][C], swizzled:
// c' = c ^ (((o>>1)&3)<<3).
__global__ __launch_bounds__(256) void k_wconv(const float* __restrict__ w,
                                               u16* __restrict__ wb, int O, int C) {
  int o = blockIdx.x;
  int t = threadIdx.x;
  int sp3 = ((o >> 1) & 3) << 3;
  const float* src = w + (size_t)o * C * 9;
  for (int c = t; c < C; c += 256) {
    const float* s = src + c * 9;
    float v[9];
#pragma unroll
    for (int i = 0; i < 9; ++i) v[i] = s[i];
#pragma unroll
    for (int tap = 0; tap < 9; ++tap)
      wb[(size_t)tap * O * C + (size_t)o * C + (c ^ sp3)] = f2bf(v[tap]);
  }
}

// ---------------------------------------------------------------------------
// Kernel 3: Gram GEMM G[p1][p2] = sum_c r1[p1][c]*r2[p2][c], scaled epilogue.
// grid 1024: b = bx>>2, p1-tile = (bx>>1)&1, p2-tile = bx&1. block 256 = 4 waves 2x2.
// Staging is monotonic (storage already swizzled); reads use XORed chunk offset.
__global__ __launch_bounds__(256) void k_corr(u16* featT,
                                              const float* __restrict__ s1,
                                              const float* __restrict__ s2,
                                              float* __restrict__ out) {
  __shared__ alignas(16) u16 Alds[128 * 32];
  __shared__ alignas(16) u16 Blds[128 * 32];
  __shared__ float tb[4][16][66];
  int bx = blockIdx.x;
  int b = bx >> 2;
  int p1b = ((bx >> 1) & 1) << 7;
  int p2b = (bx & 1) << 7;
  int t = threadIdx.x, l = t & 63, w = t >> 6;
  int wm = w >> 1, wn = w & 1, lr = l & 15, lq = l >> 4;
  int srow = (w << 4) + (l >> 2);
  int sq = (l & 3) << 3;                       // monotonic source chunk
  int rsz = ((lq ^ ((lr >> 1) & 3)) << 3);     // swizzled read chunk
  const size_t bbase = (size_t)b << 18;

  f32x4 acc[4][4];
#pragma unroll
  for (int i = 0; i < 4; ++i)
#pragma unroll
    for (int j = 0; j < 4; ++j) acc[i][j] = (f32x4){0.f, 0.f, 0.f, 0.f};

#pragma unroll 1
  for (int kc = 0; kc < 8; ++kc) {
    int c0 = kc << 5;
    const u16* sA = featT + bbase + ((size_t)(p1b + srow) << 10) + (c0 + sq);
    gl2lds16(sA, Alds + ((w << 4) << 5));
    gl2lds16(sA + (64 << 10), Alds + ((64 + (w << 4)) << 5));
    const u16* sB = featT + bbase + ((size_t)(p2b + srow) << 10) + (512 + c0 + sq);
    gl2lds16(sB, Blds + ((w << 4) << 5));
    gl2lds16(sB + (64 << 10), Blds + ((64 + (w << 4)) << 5));
    __syncthreads();
    bf16x8 af[4], bfr[4];
#pragma unroll
    for (int mf = 0; mf < 4; ++mf)
      af[mf] = *(const bf16x8*)(Alds + (((wm << 6) + (mf << 4) + lr) << 5) + rsz);
#pragma unroll
    for (int nf = 0; nf < 4; ++nf)
      bfr[nf] = *(const bf16x8*)(Blds + (((wn << 6) + (nf << 4) + lr) << 5) + rsz);
#pragma unroll
    for (int mf = 0; mf < 4; ++mf)
#pragma unroll
      for (int nf = 0; nf < 4; ++nf)
        acc[mf][nf] = __builtin_amdgcn_mfma_f32_16x16x32_bf16(af[mf], bfr[nf], acc[mf][nf], 0, 0, 0);
    __syncthreads();
  }

  float sc2[4]; int p2g[4];
#pragma unroll
  for (int nf = 0; nf < 4; ++nf) {
    int p2 = p2b + (wn << 6) + (nf << 4) + lr;
    p2g[nf] = p2;
    sc2[nf] = s2[(b << 8) + p2];
  }
  float* corr1 = out + 512;
  float* corr2 = out + 512 + 16777216;
#pragma unroll
  for (int mf = 0; mf < 4; ++mf) {
    float gv[4][4];
#pragma unroll
    for (int r = 0; r < 4; ++r) {
      int p1 = p1b + (wm << 6) + (mf << 4) + (lq << 2) + r;
      float s1v = s1[(b << 8) + p1];
#pragma unroll
      for (int nf = 0; nf < 4; ++nf) gv[nf][r] = acc[mf][nf][r] * s1v * sc2[nf];
    }
    // direct-layout writes: corr2[p1][p2] f32 (unswizzled output buffer),
    // featT[p1][256+p2] bf16 stored swizzled by ((p1>>1)&3).
#pragma unroll
    for (int r = 0; r < 4; ++r) {
      int p1 = p1b + (wm << 6) + (mf << 4) + (lq << 2) + r;
      int s1p3 = ((p1 >> 1) & 3) << 3;
#pragma unroll
      for (int nf = 0; nf < 4; ++nf) {
        corr2[((size_t)b << 16) + ((size_t)p1 << 8) + p2g[nf]] = gv[nf][r];
        featT[bbase + ((size_t)p1 << 10) + 256 + (p2g[nf] ^ s1p3)] = f2bf(gv[nf][r]);
      }
    }
    // transposed writes via LDS: corr1[p2][p1] f32 (unswizzled output buffer),
    // featT[p2][768+p1] bf16 stored swizzled by ((p2>>1)&3).
#pragma unroll
    for (int r = 0; r < 4; ++r)
#pragma unroll
      for (int nf = 0; nf < 4; ++nf)
        tb[w][(lq << 2) + r][(nf << 4) + lr] = gv[nf][r];
#pragma unroll
    for (int j = 0; j < 16; ++j) {
      float v = tb[w][lr][(j << 2) + lq];
      int p2 = p2b + (wn << 6) + (j << 2) + lq;
      int s2p3 = ((p2 >> 1) & 3) << 3;
      int p1 = p1b + (wm << 6) + (mf << 4) + lr;
      corr1[((size_t)b << 16) + ((size_t)p2 << 8) + p1] = v;
      featT[bbase + ((size_t)p2 << 10) + 768 + (p1 ^ s2p3)] = f2bf(v);
    }
  }
}

// ---------------------------------------------------------------------------
// Kernel 4/5: implicit-GEMM 3x3 conv, D[p][o] = sum_{c,tap} X[p'(p,tap)][c]*W[tap][o][c].
// Block = whole image M=256 x N=128 o, 512 threads = 8 waves (4 M x 2 N) of 64x64 tiles.
// K-pipeline: one barrier per (kc,tap) step; stages issued AFTER the barrier into
// double-buffered W (8 KB) / X (16 KB) so the barrier's vmcnt(0) only drains loads
// issued a full compute-period earlier. Border masking via zero-row redirect.
// X/W inputs and Out output are all in the swizzled storage format; gl2lds staging
// is monotonic, LDS fragment reads use the XORed chunk offsets (conflict-free).
template <int O, int OTB>
__global__ __launch_bounds__(512, 4) void k_conv(const u16* __restrict__ X,
                                                 const u16* __restrict__ Wb,
                                                 const float* __restrict__ bias,
                                                 u16* __restrict__ Out) {
  __shared__ alignas(16) u16 Xlds[2][260 * 32];  // rows 0..255 data, row 256 = zeros
  __shared__ alignas(16) u16 Wlds[2][128 * 32];
  int bx = blockIdx.x;
  int otile = bx & ((1 << OTB) - 1);   // low bits -> XCD affinity for the W slice
  int b = bx >> OTB;
  int t = threadIdx.x, l = t & 63, w = t >> 6;
  int wm = w & 3, wn = w >> 2;
  int lr = l & 15, lq = l >> 4;
  int o0 = otile << 7;
  int srl = l >> 2;
  int sq = (l & 3) << 3;               // monotonic source chunk
  const size_t xbase = (size_t)b << 18;

  const u16* wsrc = Wb + (((size_t)(o0 + (w << 4) + srl)) << 10) + sq;
  const u16* xsrc0 = X + xbase + (((size_t)((w << 4) + srl)) << 10) + sq;
  const u16* xsrc1 = xsrc0 + ((size_t)128 << 10);

  u16* wdst0 = &Wlds[0][(w << 4) << 5];
  u16* wdst1 = &Wlds[1][(w << 4) << 5];
  u16* xdA0 = &Xlds[0][(w << 4) << 5];
  u16* xdA1 = &Xlds[0][(128 + (w << 4)) << 5];
  u16* xdB0 = &Xlds[1][(w << 4) << 5];
  u16* xdB1 = &Xlds[1][(128 + (w << 4)) << 5];

  // W read: row = (wn<<6)+(nf<<4)+lr -> stored swizzle ((row>>1)&3) == ((lr>>1)&3),
  // independent of nf => fold into the precomputed base.
  int rszw = ((lq ^ ((lr >> 1) & 3)) << 3);
  const u16* bwb0 = &Wlds[0][(((wn << 6) + lr) << 5) + rszw];
  const u16* bwb1 = &Wlds[1][(((wn << 6) + lr) << 5) + rszw];

  // X read: row = (wm<<6)+(mf<<4)+lr + dr*16 + dc -> swizzle term ((lr+dc)>>1)&3,
  // independent of mf/wm/dr => 3 precomputed variants indexed by dc.
  int pb[4];
#pragma unroll
  for (int mf = 0; mf < 4; ++mf)
    pb[mf] = (((wm << 6) + (mf << 4) + lr) << 5);
  int xsz[3];
#pragma unroll
  for (int d = 0; d < 3; ++d)
    xsz[d] = ((lq ^ (((lr + d - 1) >> 1) & 3)) << 3);
  const int zoff = (256 << 5) + (lq << 3);   // zero row: any chunk is zeros

  f32x4 acc[4][4];
#pragma unroll
  for (int i = 0; i < 4; ++i)
#pragma unroll
    for (int j = 0; j < 4; ++j) acc[i][j] = (f32x4){0.f, 0.f, 0.f, 0.f};

  if (t < 32) ((unsigned*)&Xlds[t >> 4][256 << 5])[t & 15] = 0u;

  // prologue: stage X(kc=0) -> buf0, W(kc=0,tap=0) -> buf0
  gl2lds16(xsrc0, xdA0);
  gl2lds16(xsrc1, xdA1);
  gl2lds16(wsrc, wdst0);

  auto kcbody = [&](auto oddc, int kc) {
    constexpr bool ODD = decltype(oddc)::value;
    const u16* xb = ODD ? &Xlds[1][0] : &Xlds[0][0];
#pragma unroll
    for (int tap = 0; tap < 9; ++tap) {
      __syncthreads();
      // stage W for step s+1 into buf[(s+1)&1]; s parity = (kc+tap)&1
      int ntap = (tap == 8) ? 0 : tap + 1;
      int nkc = (tap == 8) ? kc + 1 : kc;   // harmless OOB garbage at very end (in-ws)
      bool np1 = ((ODD ? 1 : 0) ^ (tap & 1)) == 0;
      gl2lds16(wsrc + (size_t)ntap * ((size_t)O << 10) + (nkc << 5), np1 ? wdst1 : wdst0);
      if (tap == 0) {  // stage X(kc+1) into the other X buffer (needed 9 steps later)
        if (ODD) { gl2lds16(xsrc0 + ((kc + 1) << 5), xdA0); gl2lds16(xsrc1 + ((kc + 1) << 5), xdA1); }
        else     { gl2lds16(xsrc0 + ((kc + 1) << 5), xdB0); gl2lds16(xsrc1 + ((kc + 1) << 5), xdB1); }
      }
      const u16* bwb = (((ODD ? 1 : 0) ^ (tap & 1)) == 1) ? bwb1 : bwb0;
      bf16x8 bwf[4];
#pragma unroll
      for (int nf = 0; nf < 4; ++nf) bwf[nf] = *(const bf16x8*)(bwb + (nf << 9));
      const int dr = tap / 3 - 1, dc = tap % 3 - 1;
      const int dpo = (((dr << 4) + dc) << 5) + xsz[dc + 1];
      bf16x8 axf[4];
#pragma unroll
      for (int mf = 0; mf < 4; ++mf) {
        int rr = (wm << 2) + mf + dr;
        bool v = ((unsigned)rr < 16u) & ((unsigned)(lr + dc) < 16u);
        int off = v ? (pb[mf] + dpo) : zoff;
        axf[mf] = *(const bf16x8*)(xb + off);
      }
#pragma unroll
      for (int mf = 0; mf < 4; ++mf)
#pragma unroll
        for (int nf = 0; nf < 4; ++nf)
          acc[mf][nf] = __builtin_amdgcn_mfma_f32_16x16x32_bf16(axf[mf], bwf[nf], acc[mf][nf], 0, 0, 0);
    }
  };

#pragma unroll 1
  for (int kc2 = 0; kc2 < 16; ++kc2) {
    kcbody(BC<false>{}, 2 * kc2);
    kcbody(BC<true>{}, 2 * kc2 + 1);
  }

  float bv[4]; int og[4];
#pragma unroll
  for (int nf = 0; nf < 4; ++nf) {
    og[nf] = o0 + (wn << 6) + (nf << 4) + lr;
    bv[nf] = bias[og[nf]];
  }
#pragma unroll
  for (int mf = 0; mf < 4; ++mf)
#pragma unroll
    for (int r = 0; r < 4; ++r) {
      int p = (wm << 6) + (mf << 4) + (lq << 2) + r;
      int spp = ((p >> 1) & 3) << 3;   // swizzled output storage
      size_t rb = (size_t)((b << 8) + p) * O;
#pragma unroll
      for (int nf = 0; nf < 4; ++nf) {
        float vv = acc[mf][nf][r] + bv[nf];
        Out[rb + (og[nf] ^ spp)] = f2bf(vv > 0.f ? vv : 0.f);
      }
    }
}

// ---------------------------------------------------------------------------
// Kernel 6: cls head. Only diagonal PSROI channels survive:
// score[b][c] = mean_p relu( sum_ch out2T[b][p][ch] * Wc[c*256+p][ch] ), softmax over c.
// X2 rows are in swizzled storage: stored 16B chunk ii holds logical chunk
// ii ^ ((p>>1)&3) within each 4-chunk group; iterate logical chunks, load permuted.
__global__ __launch_bounds__(256) void k_cls(const u16* __restrict__ X2,
                                             const float* __restrict__ Wc,
                                             float* __restrict__ out) {
  int b = blockIdx.x, p = threadIdx.x;
  int s = (p >> 1) & 3;
  const uint4* xv = (const uint4*)(X2 + (((size_t)(b << 8) + p) << 9));
  const float4* w0 = (const float4*)(Wc + ((size_t)p << 9));
  const float4* w1 = (const float4*)(Wc + ((size_t)(256 + p) << 9));
  float a0 = 0.f, a1 = 0.f;
#pragma unroll 4
  for (int i = 0; i < 64; ++i) {
    int ii = (i & ~3) | ((i & 3) ^ s);   // stored chunk holding logical chunk i
    uint4 u = xv[ii];
    float x0 = bf2f((u16)(u.x & 0xffffu)), x1 = bf2f((u16)(u.x >> 16));
    float x2 = bf2f((u16)(u.y & 0xffffu)), x3 = bf2f((u16)(u.y >> 16));
    float x4 = bf2f((u16)(u.z & 0xffffu)), x5 = bf2f((u16)(u.z >> 16));
    float x6 = bf2f((u16)(u.w & 0xffffu)), x7 = bf2f((u16)(u.w >> 16));
    float4 wa = w0[i * 2], wb = w0[i * 2 + 1];
    a0 += x0 * wa.x + x1 * wa.y + x2 * wa.z + x3 * wa.w +
          x4 * wb.x + x5 * wb.y + x6 * wb.z + x7 * wb.w;
    float4 wc4 = w1[i * 2], wd = w1[i * 2 + 1];
    a1 += x0 * wc4.x + x1 * wc4.y + x2 * wc4.z + x3 * wc4.w +
          x4 * wd.x + x5 * wd.y + x6 * wd.z + x7 * wd.w;
  }
  a0 = fmaxf(a0, 0.f);
  a1 = fmaxf(a1, 0.f);
  __shared__ float r0[256], r1[256];
  r0[p] = a0; r1[p] = a1;
  for (int sdx = 128; sdx > 0; sdx >>= 1) {
    __syncthreads();
    if (p < sdx) { r0[p] += r0[p + sdx]; r1[p] += r1[p + sdx]; }
  }
  __syncthreads();
  if (p == 0) {
    float s0 = r0[0] * (1.f / 256.f), s1v = r1[0] * (1.f / 256.f);
    float m = fmaxf(s0, s1v);
    float e0 = expf(s0 - m), e1 = expf(s1v - m);
    float inv = 1.f / (e0 + e1);
    out[(b << 1) + 0] = e0 * inv;
    out[(b << 1) + 1] = e1 * inv;
  }
}

// ---------------------------------------------------------------------------
extern "C" void kernel_launch(void* const* d_in, const int* in_sizes, int n_in,
                              void* d_out, int out_size, void* d_ws, size_t ws_size,
                              hipStream_t stream) {
  const float* f1 = (const float*)d_in[0];
  const float* f2 = (const float*)d_in[1];
  const float* w1 = (const float*)d_in[2];
  const float* b1 = (const float*)d_in[3];
  const float* w2 = (const float*)d_in[4];
  const float* b2 = (const float*)d_in[5];
  const float* wc = (const float*)d_in[6];
  float* out = (float*)d_out;
  char* ws = (char*)d_ws;

  u16* featT = (u16*)(ws + 0);
  u16* out1T = (u16*)(ws + 134217728);
  u16* W1b   = (u16*)(ws + 268435456);
  u16* W2b   = (u16*)(ws + 287309824);
  float* s1  = (float*)(ws + 296747008);
  float* s2  = (float*)(ws + 297009152);
  u16* out2T = (u16*)(ws + 0);  // overlays featT (dead after conv1)

  k_norm<<<1024, 256, 0, stream>>>(f1, f2, featT, s1, s2);
  k_wconv<<<1024, 256, 0, stream>>>(w1, W1b, 1024, 1024);
  k_wconv<<<512, 256, 0, stream>>>(w2, W2b, 512, 1024);
  k_corr<<<1024, 256, 0, stream>>>(featT, s1, s2, out);
  k_conv<1024, 3><<<2048, 512, 0, stream>>>(featT, W1b, b1, out1T);
  k_conv<512, 2><<<1024, 512, 0, stream>>>(out1T, W2b, b2, out2T);
  k_cls<<<256, 256, 0, stream>>>(out2T, wc, out);
}

// Round 4
// 1901.810 us; speedup vs baseline: 1.2260x; 1.2260x over previous
//
#include <hip/hip_runtime.h>

// Shapes: BS=256, C=256, H=W=16, HW=256, conv1: 1024->1024 3x3, conv2: 1024->512 3x3,
// cls: 512->512 1x1 (only diagonal of PSROI needed -> 2 dots/pixel).
//
// Workspace layout (bytes):
//   featT  @ 0          : bf16 [256 b][256 p][1024 ch]  = 134217728   (ch: r1|corr1|r2|corr2)
//   out1T  @ 134217728  : bf16 [256 b][256 p][1024 o]   = 134217728
//   W1b    @ 268435456  : bf16 [9][1024][1024]          = 18874368
//   W2b    @ 287309824  : bf16 [9][512][1024]           = 9437184
//   s1     @ 296747008  : f32  [256*256]                = 262144
//   s2     @ 297009152  : f32  [256*256]                = 262144
//   out2T  @ 0 (overlays featT, dead after conv1): bf16 [256][256][512] = 67108864
//
// SWIZZLED STORAGE FORMAT: every bf16 row-major tensor above stores each 64B slice
// (4 x 16B chunks) with chunk index XORed by ((row>>1)&3), row = pixel p (featT/out1T/
// out2T) or out-channel o (W1b/W2b). This makes the [row][32 u16] LDS tiles conflict-
// free on ds_read_b128 (1.72e8 -> 2.4e7 conflict cycles) while keeping gl2lds sources
// monotonic. Lesson from r1/r2: scalar u16 stores scattered by the XOR break full-line
// write merging (WRITE_SIZE 2x, write-allocate evicts W from L2 -> FETCH 2x) -> the
// conv epilogue must emit aligned 16B chunk stores covering whole 64B groups.
//
// k_conv pipeline (r3, resubmitted r4 after infra failure): counted vmcnt instead of
// __syncthreads' vmcnt(0) drain. W prefetch depth 2 (3 LDS buffers, index s%3 ==
// tap%3 compile-time); X depth 1 (2 buffers, kc parity, staged at tap0, 9 steps of
// slack). Pre-barrier s_waitcnt vmcnt(N): N=3 at taps 0,1 (the 2 X loads + next W may
// stay in flight), N=1 otherwise (only next W). Wait is BEFORE s_barrier so each wave
// guarantees its own staging contribution landed; barrier publishes all waves'.

typedef __attribute__((ext_vector_type(8))) __bf16 bf16x8;
typedef __attribute__((ext_vector_type(4))) float f32x4;
typedef unsigned short u16;

template <bool B> struct BC { static constexpr bool value = B; };

__device__ __forceinline__ u16 f2bf(float f) {
  union { float f; unsigned u; } v; v.f = f;
  unsigned u = v.u;
  u += 0x7fffu + ((u >> 16) & 1u);   // RNE
  return (u16)(u >> 16);
}
__device__ __forceinline__ float bf2f(u16 h) {
  union { unsigned u; float f; } v; v.u = ((unsigned)h) << 16;
  return v.f;
}
__device__ __forceinline__ void gl2lds16(const void* g, void* l) {
  __builtin_amdgcn_global_load_lds(
      (__attribute__((address_space(1))) void*)(void*)g,
      (__attribute__((address_space(3))) void*)l, 16, 0, 0);
}

// ---------------------------------------------------------------------------
// Kernel 1: relu + channel-L2-norm scales + bf16 transpose to featT[b][p][ch].
// Stores in swizzled format: ch' = ch ^ (((p>>1)&3)<<3).
__global__ __launch_bounds__(256) void k_norm(const float* __restrict__ f1,
                                              const float* __restrict__ f2,
                                              u16* __restrict__ featT,
                                              float* __restrict__ s1,
                                              float* __restrict__ s2) {
  int bx = blockIdx.x;
  int b = bx >> 2;
  int p0 = (bx & 3) << 6;
  int t = threadIdx.x;
  int p = p0 + (t & 63);
  int cg = t >> 6;
  int sp3 = ((p >> 1) & 3) << 3;
  const float* F1 = f1 + ((size_t)b << 16);
  const float* F2 = f2 + ((size_t)b << 16);
  u16* FT = featT + (((size_t)(b << 8) + p) << 10);
  float ss1 = 0.f, ss2 = 0.f;
  for (int i = 0; i < 64; ++i) {
    int c = (cg << 6) + i;
    float v1 = F1[(c << 8) + p]; v1 = v1 > 0.f ? v1 : 0.f;
    float v2 = F2[(c << 8) + p]; v2 = v2 > 0.f ? v2 : 0.f;
    ss1 += v1 * v1; ss2 += v2 * v2;
    FT[c ^ sp3] = f2bf(v1);
    FT[512 + (c ^ sp3)] = f2bf(v2);
  }
  __shared__ float l1[256], l2[256];
  l1[t] = ss1; l2[t] = ss2;
  __syncthreads();
  if (t < 64) {
    float a = l1[t] + l1[t + 64] + l1[t + 128] + l1[t + 192];
    float c2 = l2[t] + l2[t + 64] + l2[t + 128] + l2[t + 192];
    int pp = (b << 8) + p0 + t;
    s1[pp] = 1.f / fmaxf(sqrtf(a), 1e-12f);
    s2[pp] = 1.f / fmaxf(sqrtf(c2), 1e-12f);
  }
}

// ---------------------------------------------------------------------------
// Kernel 2: weight repack fp32 [O][C][3][3] -> bf16 [tap][O][C], swizzled:
// c' = c ^ (((o>>1)&3)<<3).
__global__ __launch_bounds__(256) void k_wconv(const float* __restrict__ w,
                                               u16* __restrict__ wb, int O, int C) {
  int o = blockIdx.x;
  int t = threadIdx.x;
  int sp3 = ((o >> 1) & 3) << 3;
  const float* src = w + (size_t)o * C * 9;
  for (int c = t; c < C; c += 256) {
    const float* s = src + c * 9;
    float v[9];
#pragma unroll
    for (int i = 0; i < 9; ++i) v[i] = s[i];
#pragma unroll
    for (int tap = 0; tap < 9; ++tap)
      wb[(size_t)tap * O * C + (size_t)o * C + (c ^ sp3)] = f2bf(v[tap]);
  }
}

// ---------------------------------------------------------------------------
// Kernel 3: Gram GEMM G[p1][p2] = sum_c r1[p1][c]*r2[p2][c], scaled epilogue.
// grid 1024: b = bx>>2, p1-tile = (bx>>1)&1, p2-tile = bx&1. block 256 = 4 waves 2x2.
// Staging is monotonic (storage already swizzled); reads use XORed chunk offset.
__global__ __launch_bounds__(256) void k_corr(u16* featT,
                                              const float* __restrict__ s1,
                                              const float* __restrict__ s2,
                                              float* __restrict__ out) {
  __shared__ alignas(16) u16 Alds[128 * 32];
  __shared__ alignas(16) u16 Blds[128 * 32];
  __shared__ float tb[4][16][66];
  int bx = blockIdx.x;
  int b = bx >> 2;
  int p1b = ((bx >> 1) & 1) << 7;
  int p2b = (bx & 1) << 7;
  int t = threadIdx.x, l = t & 63, w = t >> 6;
  int wm = w >> 1, wn = w & 1, lr = l & 15, lq = l >> 4;
  int srow = (w << 4) + (l >> 2);
  int sq = (l & 3) << 3;                       // monotonic source chunk
  int rsz = ((lq ^ ((lr >> 1) & 3)) << 3);     // swizzled read chunk
  const size_t bbase = (size_t)b << 18;

  f32x4 acc[4][4];
#pragma unroll
  for (int i = 0; i < 4; ++i)
#pragma unroll
    for (int j = 0; j < 4; ++j) acc[i][j] = (f32x4){0.f, 0.f, 0.f, 0.f};

#pragma unroll 1
  for (int kc = 0; kc < 8; ++kc) {
    int c0 = kc << 5;
    const u16* sA = featT + bbase + ((size_t)(p1b + srow) << 10) + (c0 + sq);
    gl2lds16(sA, Alds + ((w << 4) << 5));
    gl2lds16(sA + (64 << 10), Alds + ((64 + (w << 4)) << 5));
    const u16* sB = featT + bbase + ((size_t)(p2b + srow) << 10) + (512 + c0 + sq);
    gl2lds16(sB, Blds + ((w << 4) << 5));
    gl2lds16(sB + (64 << 10), Blds + ((64 + (w << 4)) << 5));
    __syncthreads();
    bf16x8 af[4], bfr[4];
#pragma unroll
    for (int mf = 0; mf < 4; ++mf)
      af[mf] = *(const bf16x8*)(Alds + (((wm << 6) + (mf << 4) + lr) << 5) + rsz);
#pragma unroll
    for (int nf = 0; nf < 4; ++nf)
      bfr[nf] = *(const bf16x8*)(Blds + (((wn << 6) + (nf << 4) + lr) << 5) + rsz);
#pragma unroll
    for (int mf = 0; mf < 4; ++mf)
#pragma unroll
      for (int nf = 0; nf < 4; ++nf)
        acc[mf][nf] = __builtin_amdgcn_mfma_f32_16x16x32_bf16(af[mf], bfr[nf], acc[mf][nf], 0, 0, 0);
    __syncthreads();
  }

  float sc2[4]; int p2g[4];
#pragma unroll
  for (int nf = 0; nf < 4; ++nf) {
    int p2 = p2b + (wn << 6) + (nf << 4) + lr;
    p2g[nf] = p2;
    sc2[nf] = s2[(b << 8) + p2];
  }
  float* corr1 = out + 512;
  float* corr2 = out + 512 + 16777216;
#pragma unroll
  for (int mf = 0; mf < 4; ++mf) {
    float gv[4][4];
#pragma unroll
    for (int r = 0; r < 4; ++r) {
      int p1 = p1b + (wm << 6) + (mf << 4) + (lq << 2) + r;
      float s1v = s1[(b << 8) + p1];
#pragma unroll
      for (int nf = 0; nf < 4; ++nf) gv[nf][r] = acc[mf][nf][r] * s1v * sc2[nf];
    }
    // direct-layout writes: corr2[p1][p2] f32 (unswizzled output buffer),
    // featT[p1][256+p2] bf16 stored swizzled by ((p1>>1)&3).
#pragma unroll
    for (int r = 0; r < 4; ++r) {
      int p1 = p1b + (wm << 6) + (mf << 4) + (lq << 2) + r;
      int s1p3 = ((p1 >> 1) & 3) << 3;
#pragma unroll
      for (int nf = 0; nf < 4; ++nf) {
        corr2[((size_t)b << 16) + ((size_t)p1 << 8) + p2g[nf]] = gv[nf][r];
        featT[bbase + ((size_t)p1 << 10) + 256 + (p2g[nf] ^ s1p3)] = f2bf(gv[nf][r]);
      }
    }
    // transposed writes via LDS: corr1[p2][p1] f32 (unswizzled output buffer),
    // featT[p2][768+p1] bf16 stored swizzled by ((p2>>1)&3).
#pragma unroll
    for (int r = 0; r < 4; ++r)
#pragma unroll
      for (int nf = 0; nf < 4; ++nf)
        tb[w][(lq << 2) + r][(nf << 4) + lr] = gv[nf][r];
#pragma unroll
    for (int j = 0; j < 16; ++j) {
      float v = tb[w][lr][(j << 2) + lq];
      int p2 = p2b + (wn << 6) + (j << 2) + lq;
      int s2p3 = ((p2 >> 1) & 3) << 3;
      int p1 = p1b + (wm << 6) + (mf << 4) + lr;
      corr1[((size_t)b << 16) + ((size_t)p2 << 8) + p1] = v;
      featT[bbase + ((size_t)p2 << 10) + 768 + (p1 ^ s2p3)] = f2bf(v);
    }
  }
}

// ---------------------------------------------------------------------------
// Kernel 4/5: implicit-GEMM 3x3 conv, D[p][o] = sum_{c,tap} X[p'(p,tap)][c]*W[tap][o][c].
// Block = whole image M=256 x N=128 o, 512 threads = 8 waves (4 M x 2 N) of 64x64 tiles.
// Counted-vmcnt pipeline: W staged 2 steps ahead into Wlds[(s+2)%3]; X staged at tap0
// into the other parity buffer (9 steps slack). Pre-barrier s_waitcnt vmcnt(3|1) keeps
// prefetch in flight across barriers (no vmcnt(0) drain in the main loop).
// Epilogue: per-wave LDS transpose -> aligned uint4 stores in swizzled storage order,
// 4 lanes fully covering each 64B group (full-line write merging, no write-allocate).
template <int O, int OTB>
__global__ __launch_bounds__(512, 4) void k_conv(const u16* __restrict__ X,
                                                 const u16* __restrict__ Wb,
                                                 const float* __restrict__ bias,
                                                 u16* __restrict__ Out) {
  __shared__ alignas(16) u16 Xlds[2][260 * 32];  // rows 0..255 data, row 256 = zeros
  __shared__ alignas(16) u16 Wlds[3][128 * 32];
  int bx = blockIdx.x;
  int otile = bx & ((1 << OTB) - 1);   // low bits -> XCD affinity for the W slice
  int b = bx >> OTB;
  int t = threadIdx.x, l = t & 63, w = t >> 6;
  int wm = w & 3, wn = w >> 2;
  int lr = l & 15, lq = l >> 4;
  int o0 = otile << 7;
  int srl = l >> 2;
  int sq = (l & 3) << 3;               // monotonic source chunk
  const size_t xbase = (size_t)b << 18;

  const u16* wsrc = Wb + (((size_t)(o0 + (w << 4) + srl)) << 10) + sq;
  const u16* xsrc0 = X + xbase + (((size_t)((w << 4) + srl)) << 10) + sq;
  const u16* xsrc1 = xsrc0 + ((size_t)128 << 10);

  u16* wdst0 = &Wlds[0][(w << 4) << 5];
  u16* wdst1 = &Wlds[1][(w << 4) << 5];
  u16* wdst2 = &Wlds[2][(w << 4) << 5];
  u16* xdA0 = &Xlds[0][(w << 4) << 5];
  u16* xdA1 = &Xlds[0][(128 + (w << 4)) << 5];
  u16* xdB0 = &Xlds[1][(w << 4) << 5];
  u16* xdB1 = &Xlds[1][(128 + (w << 4)) << 5];

  // W read: row = (wn<<6)+(nf<<4)+lr -> stored swizzle ((row>>1)&3) == ((lr>>1)&3).
  int rszw = ((lq ^ ((lr >> 1) & 3)) << 3);
  const u16* bwb0 = &Wlds[0][(((wn << 6) + lr) << 5) + rszw];
  const u16* bwb1 = &Wlds[1][(((wn << 6) + lr) << 5) + rszw];
  const u16* bwb2 = &Wlds[2][(((wn << 6) + lr) << 5) + rszw];

  // X read swizzle variants indexed by dc (storage keyed on row = pixel).
  int pb[4];
#pragma unroll
  for (int mf = 0; mf < 4; ++mf)
    pb[mf] = (((wm << 6) + (mf << 4) + lr) << 5);
  int xsz[3];
#pragma unroll
  for (int d = 0; d < 3; ++d)
    xsz[d] = ((lq ^ (((lr + d - 1) >> 1) & 3)) << 3);
  const int zoff = (256 << 5) + (lq << 3);   // zero row: any chunk is zeros

  f32x4 acc[4][4];
#pragma unroll
  for (int i = 0; i < 4; ++i)
#pragma unroll
    for (int j = 0; j < 4; ++j) acc[i][j] = (f32x4){0.f, 0.f, 0.f, 0.f};

  if (t < 32) ((unsigned*)&Xlds[t >> 4][256 << 5])[t & 15] = 0u;

  // prologue: X(kc=0) -> Xbuf0, W(step0)=W(kc0,tap0) -> Wlds[0], W(step1) -> Wlds[1]
  gl2lds16(xsrc0, xdA0);
  gl2lds16(xsrc1, xdA1);
  gl2lds16(wsrc, wdst0);
  gl2lds16(wsrc + ((size_t)O << 10), wdst1);
  __syncthreads();   // full drain once at startup

  auto kcbody = [&](auto oddc, int kc) {
    constexpr bool ODD = decltype(oddc)::value;
    const u16* xb = ODD ? &Xlds[1][0] : &Xlds[0][0];
#pragma unroll
    for (int tap = 0; tap < 9; ++tap) {
      // entry: barrier passed; data for this step resident and published.
      __builtin_amdgcn_sched_barrier(0);
      // --- issue stage for step s+2: W(tap+2 [, kc+1]) ---
      int ntap = (tap + 2) % 9;
      int nkc = kc + (tap >= 7 ? 1 : 0);   // kc=31 tail reads in-ws garbage (dead)
      u16* wd = ((tap + 2) % 3 == 0) ? wdst0 : (((tap + 2) % 3 == 1) ? wdst1 : wdst2);
      gl2lds16(wsrc + (size_t)ntap * ((size_t)O << 10) + (nkc << 5), wd);
      if (tap == 0) {  // stage X(kc+1) into the other parity buffer (9-step slack)
        if (ODD) { gl2lds16(xsrc0 + ((kc + 1) << 5), xdA0); gl2lds16(xsrc1 + ((kc + 1) << 5), xdA1); }
        else     { gl2lds16(xsrc0 + ((kc + 1) << 5), xdB0); gl2lds16(xsrc1 + ((kc + 1) << 5), xdB1); }
      }
      // --- fragment reads for this step ---
      const u16* bwb = (tap % 3 == 0) ? bwb0 : ((tap % 3 == 1) ? bwb1 : bwb2);
      bf16x8 bwf[4];
#pragma unroll
      for (int nf = 0; nf < 4; ++nf) bwf[nf] = *(const bf16x8*)(bwb + (nf << 9));
      const int dr = tap / 3 - 1, dc = tap % 3 - 1;
      const int dpo = (((dr << 4) + dc) << 5) + xsz[dc + 1];
      bf16x8 axf[4];
#pragma unroll
      for (int mf = 0; mf < 4; ++mf) {
        int rr = (wm << 2) + mf + dr;
        bool v = ((unsigned)rr < 16u) & ((unsigned)(lr + dc) < 16u);
        int off = v ? (pb[mf] + dpo) : zoff;
        axf[mf] = *(const bf16x8*)(xb + off);
      }
      // --- MFMA ---
#pragma unroll
      for (int mf = 0; mf < 4; ++mf)
#pragma unroll
        for (int nf = 0; nf < 4; ++nf)
          acc[mf][nf] = __builtin_amdgcn_mfma_f32_16x16x32_bf16(axf[mf], bwf[nf], acc[mf][nf], 0, 0, 0);
      // --- pre-barrier counted wait: guarantee W(s+1) (own contribution) landed.
      // In-flight newer: W(s+2) [+ 2 X loads when tap==0 (issued this step) or
      // tap==1 (issued last step)] -> N=3 at taps 0,1; N=1 otherwise.
      if (tap == 0 || tap == 1) asm volatile("s_waitcnt vmcnt(3)" ::: "memory");
      else                      asm volatile("s_waitcnt vmcnt(1)" ::: "memory");
      __builtin_amdgcn_s_barrier();
    }
  };

#pragma unroll 1
  for (int kc2 = 0; kc2 < 16; ++kc2) {
    kcbody(BC<false>{}, 2 * kc2);
    kcbody(BC<true>{}, 2 * kc2 + 1);
  }

  // ---- epilogue: per-wave LDS transpose -> vectorized swizzled stores ----
  __syncthreads();   // drain outstanding prefetch; LDS reusable as scratch
  float bv[4];
#pragma unroll
  for (int nf = 0; nf < 4; ++nf) bv[nf] = bias[o0 + (wn << 6) + (nf << 4) + lr];
  u16* scr = ((u16*)Xlds) + w * 1152;   // per-wave 16 rows x 72 u16 (144B rows, 16B-aligned)
  int rr2 = l >> 2;                     // 4 lanes per row
  int kq = l & 3;
#pragma unroll
  for (int mf = 0; mf < 4; ++mf) {
    // write phase: logical col = nf*16+lr, row rr = lq*4+r
#pragma unroll
    for (int r = 0; r < 4; ++r) {
      int rr = (lq << 2) + r;
#pragma unroll
      for (int nf = 0; nf < 4; ++nf) {
        float vv = acc[mf][nf][r] + bv[nf];
        scr[rr * 72 + (nf << 4) + lr] = f2bf(vv > 0.f ? vv : 0.f);
      }
    }
    asm volatile("s_waitcnt lgkmcnt(0)" ::: "memory");
    __builtin_amdgcn_sched_barrier(0);
    // read+store phase: row p = wm*64+mf*16+rr2; 4 lanes cover each 64B group.
    int p = (wm << 6) + (mf << 4) + rr2;
    int sp = (p >> 1) & 3;
    size_t rbase = (size_t)((b << 8) + p) * O + (size_t)(o0 + (wn << 6));
#pragma unroll
    for (int j = 0; j < 2; ++j) {
      int k = (j << 2) | kq;             // stored chunk 0..7 (monotone per group)
      int kl = (j << 2) | (kq ^ sp);     // logical chunk held at stored slot k
      uint4 v = *(const uint4*)(scr + rr2 * 72 + (kl << 3));
      *(uint4*)(Out + rbase + (k << 3)) = v;
    }
    // fence before next pass overwrites scratch (reads above must complete)
    asm volatile("s_waitcnt lgkmcnt(0)" ::: "memory");
    __builtin_amdgcn_sched_barrier(0);
  }
}

// ---------------------------------------------------------------------------
// Kernel 6: cls head. Only diagonal PSROI channels survive:
// score[b][c] = mean_p relu( sum_ch out2T[b][p][ch] * Wc[c*256+p][ch] ), softmax over c.
// X2 rows are in swizzled storage: stored 16B chunk ii holds logical chunk
// ii ^ ((p>>1)&3) within each 4-chunk group; iterate logical chunks, load permuted.
__global__ __launch_bounds__(256) void k_cls(const u16* __restrict__ X2,
                                             const float* __restrict__ Wc,
                                             float* __restrict__ out) {
  int b = blockIdx.x, p = threadIdx.x;
  int s = (p >> 1) & 3;
  const uint4* xv = (const uint4*)(X2 + (((size_t)(b << 8) + p) << 9));
  const float4* w0 = (const float4*)(Wc + ((size_t)p << 9));
  const float4* w1 = (const float4*)(Wc + ((size_t)(256 + p) << 9));
  float a0 = 0.f, a1 = 0.f;
#pragma unroll 4
  for (int i = 0; i < 64; ++i) {
    int ii = (i & ~3) | ((i & 3) ^ s);   // stored chunk holding logical chunk i
    uint4 u = xv[ii];
    float x0 = bf2f((u16)(u.x & 0xffffu)), x1 = bf2f((u16)(u.x >> 16));
    float x2 = bf2f((u16)(u.y & 0xffffu)), x3 = bf2f((u16)(u.y >> 16));
    float x4 = bf2f((u16)(u.z & 0xffffu)), x5 = bf2f((u16)(u.z >> 16));
    float x6 = bf2f((u16)(u.w & 0xffffu)), x7 = bf2f((u16)(u.w >> 16));
    float4 wa = w0[i * 2], wb = w0[i * 2 + 1];
    a0 += x0 * wa.x + x1 * wa.y + x2 * wa.z + x3 * wa.w +
          x4 * wb.x + x5 * wb.y + x6 * wb.z + x7 * wb.w;
    float4 wc4 = w1[i * 2], wd = w1[i * 2 + 1];
    a1 += x0 * wc4.x + x1 * wc4.y + x2 * wc4.z + x3 * wc4.w +
          x4 * wd.x + x5 * wd.y + x6 * wd.z + x7 * wd.w;
  }
  a0 = fmaxf(a0, 0.f);
  a1 = fmaxf(a1, 0.f);
  __shared__ float r0[256], r1[256];
  r0[p] = a0; r1[p] = a1;
  for (int sdx = 128; sdx > 0; sdx >>= 1) {
    __syncthreads();
    if (p < sdx) { r0[p] += r0[p + sdx]; r1[p] += r1[p + sdx]; }
  }
  __syncthreads();
  if (p == 0) {
    float s0 = r0[0] * (1.f / 256.f), s1v = r1[0] * (1.f / 256.f);
    float m = fmaxf(s0, s1v);
    float e0 = expf(s0 - m), e1 = expf(s1v - m);
    float inv = 1.f / (e0 + e1);
    out[(b << 1) + 0] = e0 * inv;
    out[(b << 1) + 1] = e1 * inv;
  }
}

// ---------------------------------------------------------------------------
extern "C" void kernel_launch(void* const* d_in, const int* in_sizes, int n_in,
                              void* d_out, int out_size, void* d_ws, size_t ws_size,
                              hipStream_t stream) {
  const float* f1 = (const float*)d_in[0];
  const float* f2 = (const float*)d_in[1];
  const float* w1 = (const float*)d_in[2];
  const float* b1 = (const float*)d_in[3];
  const float* w2 = (const float*)d_in[4];
  const float* b2 = (const float*)d_in[5];
  const float* wc = (const float*)d_in[6];
  float* out = (float*)d_out;
  char* ws = (char*)d_ws;

  u16* featT = (u16*)(ws + 0);
  u16* out1T = (u16*)(ws + 134217728);
  u16* W1b   = (u16*)(ws + 268435456);
  u16* W2b   = (u16*)(ws + 287309824);
  float* s1  = (float*)(ws + 296747008);
  float* s2  = (float*)(ws + 297009152);
  u16* out2T = (u16*)(ws + 0);  // overlays featT (dead after conv1)

  k_norm<<<1024, 256, 0, stream>>>(f1, f2, featT, s1, s2);
  k_wconv<<<1024, 256, 0, stream>>>(w1, W1b, 1024, 1024);
  k_wconv<<<512, 256, 0, stream>>>(w2, W2b, 512, 1024);
  k_corr<<<1024, 256, 0, stream>>>(featT, s1, s2, out);
  k_conv<1024, 3><<<2048, 512, 0, stream>>>(featT, W1b, b1, out1T);
  k_conv<512, 2><<<1024, 512, 0, stream>>>(out1T, W2b, b2, out2T);
  k_cls<<<256, 256, 0, stream>>>(out2T, wc, out);
}